// Round 1
// baseline (1141.061 us; speedup 1.0000x reference)
//
#include <hip/hip_runtime.h>

// Fused 1->288ch 3x3 VALID conv + bias(full tensor) + ReLU, fp32.
// B=16, H=W=224, HOUT=WOUT=222, COUT=288.
// Write-BW-bound: 908 MB out + 57 MB bias + 3 MB x  => ~155 us floor.
// Layout: thread = (4 consecutive flat plane positions) x (4 channels),
// batch loop innermost; bias held in regs across batches (read once).

constexpr int Bn    = 16;
constexpr int COUT  = 288;
constexpr int Hin   = 224;
constexpr int Win   = 224;
constexpr int HOUT  = 222;
constexpr int WOUT  = 222;
constexpr int PLANE = HOUT * WOUT;   // 49284, divisible by 4
constexpr int NF4   = PLANE / 4;     // 12321 float4 groups per plane
constexpr int XPLANE = Hin * Win;    // 50176

__global__ __launch_bounds__(256) void conv_bias_relu(
    const float* __restrict__ x,     // (16,1,224,224)
    const float* __restrict__ w,     // (288,1,3,3)
    const float* __restrict__ bias,  // (1,288,222,222)
    float* __restrict__ out)         // (16,288,222,222)
{
    const int f4 = blockIdx.x * blockDim.x + threadIdx.x;
    if (f4 >= NF4) return;
    const int f   = f4 * 4;
    const int co0 = blockIdx.y * 4;

    // 3x3 weights for this block's 4 channels (block-uniform)
    float wv[4][9];
    #pragma unroll
    for (int c = 0; c < 4; ++c)
        #pragma unroll
        for (int k = 0; k < 9; ++k)
            wv[c][k] = w[(co0 + c) * 9 + k];

    // per-position x offsets (batch-independent)
    int off[4];
    #pragma unroll
    for (int j = 0; j < 4; ++j) {
        unsigned fj = (unsigned)(f + j);
        unsigned ho = fj / 222u;          // magic-mul, no div instr
        unsigned wo = fj - ho * 222u;
        off[j] = (int)(ho * 224u + wo);
    }

    // bias: one float4 per channel, read ONCE, reused for all 16 batches
    float4 bv[4];
    #pragma unroll
    for (int c = 0; c < 4; ++c)
        bv[c] = *reinterpret_cast<const float4*>(bias + (size_t)(co0 + c) * PLANE + f);

    for (int b = 0; b < Bn; ++b) {
        const float* xb = x + b * XPLANE;

        float acc[4][4];  // [channel][position]
        #pragma unroll
        for (int c = 0; c < 4; ++c) {
            acc[c][0] = bv[c].x; acc[c][1] = bv[c].y;
            acc[c][2] = bv[c].z; acc[c][3] = bv[c].w;
        }

        #pragma unroll
        for (int j = 0; j < 4; ++j) {
            float xv[9];
            const float* xp = xb + off[j];
            #pragma unroll
            for (int kh = 0; kh < 3; ++kh)
                #pragma unroll
                for (int kw = 0; kw < 3; ++kw)
                    xv[kh * 3 + kw] = xp[kh * 224 + kw];

            #pragma unroll
            for (int c = 0; c < 4; ++c)
                #pragma unroll
                for (int k = 0; k < 9; ++k)
                    acc[c][j] = fmaf(wv[c][k], xv[k], acc[c][j]);
        }

        #pragma unroll
        for (int c = 0; c < 4; ++c) {
            float4 o;
            o.x = fmaxf(acc[c][0], 0.f);
            o.y = fmaxf(acc[c][1], 0.f);
            o.z = fmaxf(acc[c][2], 0.f);
            o.w = fmaxf(acc[c][3], 0.f);
            *reinterpret_cast<float4*>(
                out + (size_t)(b * COUT + co0 + c) * PLANE + f) = o;
        }
    }
}

extern "C" void kernel_launch(void* const* d_in, const int* in_sizes, int n_in,
                              void* d_out, int out_size, void* d_ws, size_t ws_size,
                              hipStream_t stream) {
    const float* x    = (const float*)d_in[0];  // 16*1*224*224
    const float* w    = (const float*)d_in[1];  // 288*1*3*3
    const float* bias = (const float*)d_in[2];  // 1*288*222*222
    float* out        = (float*)d_out;          // 16*288*222*222

    dim3 block(256);
    dim3 grid((NF4 + 255) / 256, COUT / 4);     // 49 x 72
    conv_bias_relu<<<grid, block, 0, stream>>>(x, w, bias, out);
}